// Round 19
// baseline (60.156 us; speedup 1.0000x reference)
//
#include <hip/hip_runtime.h>

typedef __attribute__((ext_vector_type(2))) float f32x2;

#define NS 1024      // N samples
#define MM 64        // M patches
#define CC 4         // C compartments
#define NSTEPS 100
#define CLIPMAX 1e10f

// Broadcast lane k's value to all lanes via v_readlane (setup only).
__device__ __forceinline__ float rdlane(float v, int k) {
    return __uint_as_float(__builtin_amdgcn_readlane(__float_as_uint(v), k));
}
// Force a (wave-uniform) value into an SGPR.
__device__ __forceinline__ float sfirst(float v) {
    return __uint_as_float(__builtin_amdgcn_readfirstlane(__float_as_uint(v)));
}

// One wave per sample, barrier-free. r15 series phase-A + r16 LDS p-broadcast
// + r18 p-pipeline + r19: TRAJECTORY STORES DECOUPLED FROM STATE REGISTERS.
// Diagnosis: ~1000 cyc/step of stall that is neither issue (~270 cyc,
// VALUBusy 21%) nor dataflow (~200 cyc) nor LDS latency (r18 pipelined it
// away, null). Prime suspect: the compiler stores the trajectory directly
// from the rh register quad, so rotating rh at step end waits vmcnt(0) for
// the store to COMPLETE at L2 (~300-900 cyc under 256-CU write contention).
// Fix: per step, ds_write_b128 the pre-update state into an 8-slot LDS ring
// (static slot index); every 8 steps flush: 8x ds_read_b128 -> 8x
// global_store_dwordx4 from 8 DISTINCT temp payload/address quads that are
// redefined only at the NEXT flush (~8 steps of slack -> any vmcnt is free).
// rh is never a store source -> rotation never waits on memory.
extern "C" __global__
__attribute__((amdgpu_flat_work_group_size(64, 64), amdgpu_waves_per_eu(1, 1)))
void metapop_kernel(
    const float* __restrict__ R,     // (NS, MM, MM)
    const float* __restrict__ T,     // (NS, CC, CC)
    const float* __restrict__ rho0,  // (NS, MM, CC)
    const float* __restrict__ beta,  // (NS,)
    float* __restrict__ out)         // (NSTEPS, NS, MM, CC)
{
    const int n    = blockIdx.x;
    const int lane = threadIdx.x;    // 0..63

    __shared__ float  bufA[MM];
    __shared__ float  bufB[MM];
    __shared__ float4 ring[8][MM];   // 8 KB trajectory ring

    const float* Rn = R + (size_t)n * (MM * MM);

    // ---- Rrow pairs ----
    f32x2 Rrow2[32];
    {
        const float4* p4 = (const float4*)(Rn + lane * MM);
        #pragma unroll
        for (int q = 0; q < 16; ++q) {
            float4 v = p4[q];
            Rrow2[2*q]   = (f32x2){v.x, v.y};
            Rrow2[2*q+1] = (f32x2){v.z, v.w};
        }
    }

    // ---- ntot[lane] = sum_i R[n,i,lane] ----
    float nt = 0.f;
    #pragma unroll
    for (int i = 0; i < MM; ++i) nt += Rn[i * MM + lane];
    const float binv = beta[n] / nt;

    // ---- G power sums (G dies here; series coefficients survive) ----
    // Rt[n,i,j] = R[(i&15)*64+j, (n&15)*4+(i>>4), n>>4]
    float S1 = 0.f, S2 = 0.f, S3 = 0.f, S4 = 0.f;
    {
        const int q     = n >> 4;
        const int a     = ((n & 15) << 2) + (lane >> 4);
        const int sbase = (lane & 15) << 6;
        #pragma unroll
        for (int j = 0; j < MM; ++j) {
            float g  = R[(size_t)(sbase + j) * (MM * MM) + a * MM + q]
                     * rdlane(binv, j);
            float g2 = g * g;
            S1 += g;  S2 += g2;  S3 += g2 * g;  S4 += g2 * g2;
        }
    }
    const float T1 = S1, T2 = 0.5f * S2,
                T3 = (1.f / 3.f) * S3, T4 = 0.25f * S4;

    #pragma unroll
    for (int q = 0; q < 32; ++q) asm volatile("" : "+v"(Rrow2[q]));

    // ---- T[n] -> SGPRs ----
    float tt[CC][CC];
    {
        const float* Tn = T + n * (CC * CC);
        #pragma unroll
        for (int k = 0; k < CC; ++k)
            #pragma unroll
            for (int l = 0; l < CC; ++l)
                tt[k][l] = sfirst(Tn[k * CC + l]);
    }

    // ---- rho0 ----
    float rh0, rh1, rh2, rh3;
    {
        float4 v = *(const float4*)(rho0 + (size_t)n * (MM * CC) + lane * CC);
        rh0 = v.x; rh1 = v.y; rh2 = v.z; rh3 = v.w;
    }

    const size_t stride = (size_t)NS * MM * CC;
    float* obase = out + (size_t)n * (MM * CC) + lane * CC;

    // ---- preheader: p_0 -> bufA ----
    {
        const float h0 = T1 + rh1 * (T2 + rh1 * (T3 + rh1 * T4));
        bufA[lane] = 1.f - __expf(-(rh1 * h0));
    }

    // One pipelined step. Reads p_t from RD (written last step), writes
    // p_{t+1} to WR, records pre-update state into ring[slot].
    auto body = [&](const float* __restrict__ RD, float* __restrict__ WR,
                    int slot) {
        // (1) issue p reads for THIS step
        float4 pv[16];
        {
            const float4* pb4 = (const float4*)RD;
            #pragma unroll
            for (int q = 0; q < 16; ++q) pv[q] = pb4[q];
        }

        // (2) pre-update state -> LDS ring (static slot -> offset immediate)
        ring[slot][lane] = make_float4(rh0, rh1, rh2, rh3);

        // (3) phase-C pre-sums + next rho[1..3]
        const float c0 = rh0*tt[0][0] + rh1*tt[1][0] + rh2*tt[2][0] + rh3*tt[3][0];
        const float c1 = rh0*tt[0][1] + rh1*tt[1][1] + rh2*tt[2][1] + rh3*tt[3][1];
        const float c2 = rh0*tt[0][2] + rh1*tt[1][2] + rh2*tt[2][2] + rh3*tt[3][2];
        const float c3 = rh0*tt[0][3] + rh1*tt[1][3] + rh2*tt[2][3] + rh3*tt[3][3];
        const float nrh1 = fminf(fmaxf(c1, 0.f), CLIPMAX);
        const float nrh2 = fminf(fmaxf(c2, 0.f), CLIPMAX);
        const float nrh3 = fminf(fmaxf(c3, 0.f), CLIPMAX);

        // (4) NEXT step's p -> the other p-buffer
        {
            const float hn = T1 + nrh1 * (T2 + nrh1 * (T3 + nrh1 * T4));
            WR[lane] = 1.f - __expf(-(nrh1 * hn));
        }

        // (5) phase B matvec on pv
        f32x2 a0 = {0.f, 0.f}, a1 = {0.f, 0.f}, a2 = {0.f, 0.f}, a3 = {0.f, 0.f};
        #pragma unroll
        for (int q = 0; q < 4; ++q) {
            float4 pvv;
            pvv = pv[q];
            a0 += Rrow2[2*q]      * (f32x2){pvv.x, pvv.y};
            a0 += Rrow2[2*q + 1]  * (f32x2){pvv.z, pvv.w};
            pvv = pv[q + 4];
            a1 += Rrow2[2*q + 8]  * (f32x2){pvv.x, pvv.y};
            a1 += Rrow2[2*q + 9]  * (f32x2){pvv.z, pvv.w};
            pvv = pv[q + 8];
            a2 += Rrow2[2*q + 16] * (f32x2){pvv.x, pvv.y};
            a2 += Rrow2[2*q + 17] * (f32x2){pvv.z, pvv.w};
            pvv = pv[q + 12];
            a3 += Rrow2[2*q + 24] * (f32x2){pvv.x, pvv.y};
            a3 += Rrow2[2*q + 25] * (f32x2){pvv.z, pvv.w};
        }
        const f32x2 aa = (a0 + a1) + (a2 + a3);
        const float ssum = aa.x + aa.y;
        const float sr   = (rh0 + rh1) + (rh2 + rh3);
        const float ninf = (1.f - sr) * ssum;

        // (6) rotate state (no store reads these registers -> no vmcnt wait)
        rh0 = fminf(fmaxf(c0 + ninf, 0.f), CLIPMAX);
        rh1 = nrh1; rh2 = nrh2; rh3 = nrh3;
    };

    // Flush CNT ring slots to global. Payload/address temporaries are
    // redefined only at the next flush (~8 steps later) -> waits are free.
    auto flush8 = [&](float* ob8) {
        #pragma unroll
        for (int j = 0; j < 8; ++j) {
            float4 v = ring[j][lane];
            *(float4*)(ob8 + (size_t)j * stride) = v;
        }
    };

    #pragma unroll 1
    for (int blk = 0; blk < 12; ++blk) {
        body(bufA, bufB, 0); body(bufB, bufA, 1);
        body(bufA, bufB, 2); body(bufB, bufA, 3);
        body(bufA, bufB, 4); body(bufB, bufA, 5);
        body(bufA, bufB, 6); body(bufB, bufA, 7);
        flush8(obase);
        obase += 8 * stride;
    }
    // tail: 4 steps + short flush
    body(bufA, bufB, 0); body(bufB, bufA, 1);
    body(bufA, bufB, 2); body(bufB, bufA, 3);
    #pragma unroll
    for (int j = 0; j < 4; ++j) {
        float4 v = ring[j][lane];
        *(float4*)(obase + (size_t)j * stride) = v;
    }
}

extern "C" void kernel_launch(void* const* d_in, const int* in_sizes, int n_in,
                              void* d_out, int out_size, void* d_ws, size_t ws_size,
                              hipStream_t stream) {
    const float* R    = (const float*)d_in[0];
    const float* T    = (const float*)d_in[1];
    const float* rho0 = (const float*)d_in[2];
    const float* beta = (const float*)d_in[3];
    float* out = (float*)d_out;
    hipLaunchKernelGGL(metapop_kernel, dim3(NS), dim3(64), 0, stream,
                       R, T, rho0, beta, out);
}